// Round 5
// baseline (226.461 us; speedup 1.0000x reference)
//
#include <hip/hip_runtime.h>

#define B_ 4
#define C_ 64
#define IC_ 32
#define N_ 4096
#define LOG2E 1.44269504088896341f

typedef __attribute__((ext_vector_type(8))) short short8;
typedef __attribute__((ext_vector_type(4))) float floatx4;

__device__ __forceinline__ unsigned short f2bf(float f) {
  unsigned u = __float_as_uint(f);
  u += 0x7FFFu + ((u >> 16) & 1u);   // round-to-nearest-even
  return (unsigned short)(u >> 16);
}
__device__ __forceinline__ float bf2f(unsigned short h) {
  return __uint_as_float(((unsigned)h) << 16);
}

// ---------------- weight pack: convs -> [tap][oc][ic] bf16; proj -> [96][64] bf16 ----------------
__global__ void __launch_bounds__(256) pack_w_k(
    const float* __restrict__ d1_w, const float* __restrict__ d2_w, const float* __restrict__ d3_w,
    const float* __restrict__ th_w, const float* __restrict__ ph_w, const float* __restrict__ g_w,
    const float* __restrict__ th_b, const float* __restrict__ ph_b, const float* __restrict__ g_b,
    unsigned short* __restrict__ wpk, unsigned short* __restrict__ wproj, float* __restrict__ bproj)
{
  const int tid = blockIdx.x * 256 + threadIdx.x;
  for (int idx = tid; idx < 3 * 36864; idx += gridDim.x * 256) {
    int cv = idx / 36864, r = idx % 36864;
    int tap = r / 4096, r2 = r % 4096;
    int oc = r2 >> 6, ic = r2 & 63;
    const float* src = (cv == 0) ? d1_w : (cv == 1) ? d2_w : d3_w;
    wpk[(size_t)cv * 36864 + tap * 4096 + oc * 64 + ic] = f2bf(src[oc * 576 + ic * 9 + tap]);
  }
  for (int idx = tid; idx < 6144; idx += gridDim.x * 256) {
    int m = idx >> 6, ic = idx & 63;
    float v = (m < 32) ? LOG2E * th_w[m * 64 + ic]
            : (m < 64) ? ph_w[(m - 32) * 64 + ic]
                       : g_w[(m - 64) * 64 + ic];
    wproj[m * 64 + ic] = f2bf(v);
  }
  for (int m = tid; m < 96; m += gridDim.x * 256) {
    bproj[m] = (m < 32) ? LOG2E * th_b[m] : (m < 64) ? ph_b[m - 32] : g_b[m - 64];
  }
}

// ---------------- pack x: [b][64c][64h][64w] f32 -> padded channel-last bf16 [b][66][66][64] ----------------
__global__ void __launch_bounds__(256) pack_x_k(
    const float* __restrict__ x, unsigned short* __restrict__ xclp)
{
  const int b = blockIdx.x >> 6, h = blockIdx.x & 63;
  const int t = threadIdx.x;
  __shared__ float s[64][65];
  for (int idx = t; idx < 4096; idx += 256) {
    int c = idx >> 6, w = idx & 63;
    s[c][w] = x[((size_t)(b * 64 + c)) * 4096 + h * 64 + w];
  }
  __syncthreads();
  for (int idx = t; idx < 4096; idx += 256) {
    int w = idx >> 6, c = idx & 63;
    xclp[(((size_t)b * 66 + h + 1) * 66 + (w + 1)) * 64 + c] = f2bf(s[c][w]);
  }
}

// ---------------- implicit-GEMM conv 3x3 s2, 64->64 ch, MFMA bf16, 1 wave/block ------
template<int IN_PW, int OUT_H, bool LRELU, bool OUT_BF16>
__global__ void __launch_bounds__(64) convmf_k(
    const unsigned short* __restrict__ xin, const unsigned short* __restrict__ wp,
    const float* __restrict__ bias, unsigned short* __restrict__ obf,
    float* __restrict__ of32)
{
  constexpr int NTILES = OUT_H * OUT_H / 16;
  const int lane = threadIdx.x;
  const int n15 = lane & 15, quad = lane >> 4;
  int bx = blockIdx.x;
  const int octile = bx & 3; bx >>= 2;
  const int otile = bx % NTILES;
  const int b = bx / NTILES;
  const int o = otile * 16 + n15;
  const int oh = o / OUT_H, ow = o % OUT_H;
  const unsigned short* xb = xin + (size_t)b * IN_PW * IN_PW * 64;
  floatx4 acc = {0.f, 0.f, 0.f, 0.f};
#pragma unroll
  for (int tap = 0; tap < 9; ++tap) {
    const int kh = tap / 3, kw = tap % 3;
    const unsigned short* xpix = xb + ((size_t)(oh * 2 + kh) * IN_PW + (ow * 2 + kw)) * 64;
#pragma unroll
    for (int ks = 0; ks < 2; ++ks) {
      short8 af = *reinterpret_cast<const short8*>(
          wp + ((size_t)tap * 64 + octile * 16 + n15) * 64 + ks * 32 + quad * 8);
      short8 bf = *reinterpret_cast<const short8*>(xpix + ks * 32 + quad * 8);
      acc = __builtin_amdgcn_mfma_f32_16x16x32_bf16(af, bf, acc, 0, 0, 0);
    }
  }
  const float4 bv = *reinterpret_cast<const float4*>(bias + octile * 16 + quad * 4);
  float v[4] = {acc[0] + bv.x, acc[1] + bv.y, acc[2] + bv.z, acc[3] + bv.w};
  if (LRELU) {
#pragma unroll
    for (int r = 0; r < 4; ++r) v[r] = (v[r] >= 0.f) ? v[r] : 0.2f * v[r];
  }
  if (OUT_BF16) {
    constexpr int OPW = OUT_H + 2;
    unsigned short pk[4];
#pragma unroll
    for (int r = 0; r < 4; ++r) pk[r] = f2bf(v[r]);
    *reinterpret_cast<uint2*>(
        obf + (((size_t)b * OPW + oh + 1) * OPW + (ow + 1)) * 64 + octile * 16 + quad * 4) =
        *reinterpret_cast<uint2*>(pk);
  } else {
    *reinterpret_cast<float4*>(
        of32 + ((size_t)b * OUT_H * OUT_H + o) * 64 + octile * 16 + quad * 4) =
        *reinterpret_cast<float4*>(v);
  }
}

// ---------------- fused: bilinear upsample + sigmoid gate + 1x1 proj MFMA ------------
// Block = (b, oh): computes am row (64 n x 64 c) -> LDS + global; then 4 waves do the
// 96x64 projection MFMAs for their 16-n tile, writing thph (bf16 cl) + g16.
__global__ void __launch_bounds__(256) upsproj_k(
    const float* __restrict__ y3cl, const float* __restrict__ x,
    const unsigned short* __restrict__ wproj, const float* __restrict__ bproj,
    unsigned short* __restrict__ am_cl, unsigned short* __restrict__ thph,
    unsigned short* __restrict__ g16)
{
  const int b = blockIdx.x >> 6, oh = blockIdx.x & 63;
  const int t = threadIdx.x;
  __shared__ float s0[512], s1[512];
  __shared__ unsigned short s_am[64][72];   // row stride 144 B: 2-way banks (free), 16B-aligned
  float sh = (oh + 0.5f) * 0.125f - 0.5f;
  float fh = floorf(sh); float ah = sh - fh; int h0 = (int)fh;
  int h0c = min(7, max(0, h0)), h1c = min(7, max(0, h0 + 1));
  const float* yb = y3cl + (size_t)b * 4096;
  for (int i = t; i < 512; i += 256) { s0[i] = yb[h0c * 512 + i]; s1[i] = yb[h1c * 512 + i]; }
  __syncthreads();
  {
    const int ow = t >> 2, cq = t & 3;
    float sw = (ow + 0.5f) * 0.125f - 0.5f;
    float fw = floorf(sw); float aw = sw - fw; int w0 = (int)fw;
    int w0c = min(7, max(0, w0)), w1c = min(7, max(0, w0 + 1));
    const int n = oh * 64 + ow;
    const float* xb = x + (size_t)b * 64 * 4096 + n;
    unsigned short* ap = am_cl + ((size_t)b * N_ + n) * 64 + cq * 16;
#pragma unroll
    for (int u = 0; u < 4; ++u) {
      int c0 = cq * 16 + u * 4;
      float4 a00 = *reinterpret_cast<const float4*>(&s0[w0c * 64 + c0]);
      float4 a01 = *reinterpret_cast<const float4*>(&s0[w1c * 64 + c0]);
      float4 a10 = *reinterpret_cast<const float4*>(&s1[w0c * 64 + c0]);
      float4 a11 = *reinterpret_cast<const float4*>(&s1[w1c * 64 + c0]);
      float i0[4] = {a00.x * (1.f - aw) + a01.x * aw, a00.y * (1.f - aw) + a01.y * aw,
                     a00.z * (1.f - aw) + a01.z * aw, a00.w * (1.f - aw) + a01.w * aw};
      float i1[4] = {a10.x * (1.f - aw) + a11.x * aw, a10.y * (1.f - aw) + a11.y * aw,
                     a10.z * (1.f - aw) + a11.z * aw, a10.w * (1.f - aw) + a11.w * aw};
      unsigned short pk[4];
#pragma unroll
      for (int vi = 0; vi < 4; ++vi) {
        float vv = i0[vi] * (1.f - ah) + i1[vi] * ah;
        float xv = xb[(size_t)(c0 + vi) * 4096];
        float sig = 1.f / (1.f + __expf(-vv));
        pk[vi] = f2bf(sig * xv);
      }
      uint2 pkt = *reinterpret_cast<uint2*>(pk);
      *reinterpret_cast<uint2*>(ap + u * 4) = pkt;
      *reinterpret_cast<uint2*>(&s_am[ow][c0]) = pkt;
    }
  }
  __syncthreads();
  // phase 2: projection for this row's 64 n
  const int wave = t >> 6, lane = t & 63;
  const int n15 = lane & 15, quad = lane >> 4;
  const int n = oh * 64 + wave * 16 + n15;
  const unsigned short* srow = &s_am[wave * 16 + n15][0];
  const short8 bf0 = *reinterpret_cast<const short8*>(srow + quad * 8);
  const short8 bf1 = *reinterpret_cast<const short8*>(srow + 32 + quad * 8);
#pragma unroll
  for (int mt = 0; mt < 6; ++mt) {
    short8 a0 = *reinterpret_cast<const short8*>(wproj + ((size_t)mt * 16 + n15) * 64 + quad * 8);
    short8 a1 = *reinterpret_cast<const short8*>(wproj + ((size_t)mt * 16 + n15) * 64 + 32 + quad * 8);
    floatx4 acc = {0.f, 0.f, 0.f, 0.f};
    acc = __builtin_amdgcn_mfma_f32_16x16x32_bf16(a0, bf0, acc, 0, 0, 0);
    acc = __builtin_amdgcn_mfma_f32_16x16x32_bf16(a1, bf1, acc, 0, 0, 0);
    const float4 bv = *reinterpret_cast<const float4*>(bproj + mt * 16 + quad * 4);
    float v[4] = {acc[0] + bv.x, acc[1] + bv.y, acc[2] + bv.z, acc[3] + bv.w};
    if (mt < 4) {
      unsigned short pk[4];
#pragma unroll
      for (int r = 0; r < 4; ++r) pk[r] = f2bf(v[r]);
      *reinterpret_cast<uint2*>(thph + ((size_t)b * N_ + n) * 64 + mt * 16 + quad * 4) =
          *reinterpret_cast<uint2*>(pk);
    } else {
#pragma unroll
      for (int r = 0; r < 4; ++r)
        g16[((size_t)b * 32 + (mt - 4) * 16 + quad * 4 + r) * N_ + n] = f2bf(v[r]);
    }
  }
}

// ---------------- pass A: l_j = sum_i exp2(S'_ij), partial over i-eighth -------------
// grid (32, B, 8); wave owns 32 j-columns, loops its 512-i slice; prefetch 4 ahead.
__global__ void __launch_bounds__(256) attn_stats_k(
    const unsigned short* __restrict__ thph, float* __restrict__ lpart)
{
  const int b  = blockIdx.y;
  const int iz = blockIdx.z;
  const int j0 = blockIdx.x * 128;
  const int t = threadIdx.x, wave = t >> 6, lane = t & 63;
  const int n15 = lane & 15, quad = lane >> 4;
  const int jw = j0 + wave * 32;
  const unsigned short* base = thph + (size_t)b * N_ * 64;
  const short8 b0 = *reinterpret_cast<const short8*>(base + (size_t)(jw + n15) * 64 + 32 + quad * 8);
  const short8 b1 = *reinterpret_cast<const short8*>(base + (size_t)(jw + 16 + n15) * 64 + 32 + quad * 8);
  float ls0 = 0.f, ls1 = 0.f;
  const unsigned short* ab = base + (size_t)(iz * 512 + n15) * 64 + quad * 8;
  short8 ac[4], an[4];
#pragma unroll
  for (int u = 0; u < 4; ++u) ac[u] = *reinterpret_cast<const short8*>(ab + (size_t)u * 1024);
  for (int blk = 0; blk < 8; ++blk) {
    const int nxt = (blk < 7) ? (blk + 1) * 4 : blk * 4;
#pragma unroll
    for (int u = 0; u < 4; ++u)
      an[u] = *reinterpret_cast<const short8*>(ab + (size_t)(nxt + u) * 1024);
#pragma unroll
    for (int u = 0; u < 4; ++u) {
      floatx4 z0 = {0.f, 0.f, 0.f, 0.f}, z1 = {0.f, 0.f, 0.f, 0.f};
      z0 = __builtin_amdgcn_mfma_f32_16x16x32_bf16(ac[u], b0, z0, 0, 0, 0);
      z1 = __builtin_amdgcn_mfma_f32_16x16x32_bf16(ac[u], b1, z1, 0, 0, 0);
      ls0 += __builtin_amdgcn_exp2f(z0[0]) + __builtin_amdgcn_exp2f(z0[1])
           + __builtin_amdgcn_exp2f(z0[2]) + __builtin_amdgcn_exp2f(z0[3]);
      ls1 += __builtin_amdgcn_exp2f(z1[0]) + __builtin_amdgcn_exp2f(z1[1])
           + __builtin_amdgcn_exp2f(z1[2]) + __builtin_amdgcn_exp2f(z1[3]);
    }
#pragma unroll
    for (int u = 0; u < 4; ++u) ac[u] = an[u];
  }
  ls0 += __shfl_xor(ls0, 16); ls0 += __shfl_xor(ls0, 32);
  ls1 += __shfl_xor(ls1, 16); ls1 += __shfl_xor(ls1, 32);
  if (quad == 0) {
    lpart[((size_t)iz * B_ + b) * N_ + jw + n15]      = ls0;
    lpart[((size_t)iz * B_ + b) * N_ + jw + 16 + n15] = ls1;
  }
}

// ---------------- fold softmax denom into g: g[c][j] *= 1/l_j (in place) ----------------
__global__ void __launch_bounds__(256) scale_g_k(
    const float* __restrict__ lpart, unsigned short* __restrict__ g16)
{
  const int b = blockIdx.y;
  const int j = blockIdx.x * 256 + threadIdx.x;
  float l = 0.f;
#pragma unroll
  for (int iz = 0; iz < 8; ++iz) l += lpart[((size_t)iz * B_ + b) * N_ + j];
  const float rl = 1.f / l;
  unsigned short* gp = g16 + (size_t)b * 32 * N_ + j;
#pragma unroll
  for (int c = 0; c < 32; ++c) {
    gp[(size_t)c * N_] = f2bf(bf2f(gp[(size_t)c * N_]) * rl);
  }
}

// ---------------- pass B: Y[i][c] += sum_j exp2(S') * gs[c][j] (gs pre-scaled) --------
// S^T trick (A=phi, B=theta) + ds_bpermute j-transform; next-chunk register prefetch;
// grid (64, B, 8); wave owns 16 i, loops its 512-j slice; atomicAdd into zeroed y2f.
__global__ void __launch_bounds__(256) attn_pv_k(
    const unsigned short* __restrict__ thph, const unsigned short* __restrict__ g16,
    float* __restrict__ y2f)
{
  const int b  = blockIdx.y;
  const int jh = blockIdx.z;
  const int t = threadIdx.x, wave = t >> 6, lane = t & 63;
  const int n15 = lane & 15, quad = lane >> 4;
  const int iw = blockIdx.x * 64 + wave * 16;
  const unsigned short* base  = thph + (size_t)b * N_ * 64;
  const unsigned short* gs    = g16  + (size_t)b * 32 * N_;
  const short8 bth = *reinterpret_cast<const short8*>(base + (size_t)(iw + n15) * 64 + quad * 8);
  const bool bsel = (quad >> 1) & 1;
  const int addr0 = (n15 + ((quad & 1) << 5)) << 2;
  const int addr1 = addr0 + 64;
  floatx4 Y0 = {0.f, 0.f, 0.f, 0.f}, Y1 = {0.f, 0.f, 0.f, 0.f};

  short8 fph[4], fg[4], nph[4], ng[4];
  int j0 = jh * 512;
#pragma unroll
  for (int js = 0; js < 4; ++js)
    fph[js] = *reinterpret_cast<const short8*>(base + (size_t)(j0 + js * 16 + n15) * 64 + 32 + quad * 8);
#pragma unroll
  for (int kc = 0; kc < 2; ++kc) {
    fg[kc * 2]     = *reinterpret_cast<const short8*>(gs + (size_t)n15 * N_ + j0 + kc * 32 + quad * 8);
    fg[kc * 2 + 1] = *reinterpret_cast<const short8*>(gs + (size_t)(16 + n15) * N_ + j0 + kc * 32 + quad * 8);
  }

  for (int ch = 0; ch < 8; ++ch, j0 += 64) {
    const int jn = (ch < 7) ? j0 + 64 : j0;
#pragma unroll
    for (int js = 0; js < 4; ++js)
      nph[js] = *reinterpret_cast<const short8*>(base + (size_t)(jn + js * 16 + n15) * 64 + 32 + quad * 8);
#pragma unroll
    for (int kc = 0; kc < 2; ++kc) {
      ng[kc * 2]     = *reinterpret_cast<const short8*>(gs + (size_t)n15 * N_ + jn + kc * 32 + quad * 8);
      ng[kc * 2 + 1] = *reinterpret_cast<const short8*>(gs + (size_t)(16 + n15) * N_ + jn + kc * 32 + quad * 8);
    }
    unsigned pk[4][2];
#pragma unroll
    for (int js = 0; js < 4; ++js) {
      floatx4 z = {0.f, 0.f, 0.f, 0.f};
      z = __builtin_amdgcn_mfma_f32_16x16x32_bf16(fph[js], bth, z, 0, 0, 0);
      float e0 = __builtin_amdgcn_exp2f(z[0]), e1 = __builtin_amdgcn_exp2f(z[1]);
      float e2 = __builtin_amdgcn_exp2f(z[2]), e3 = __builtin_amdgcn_exp2f(z[3]);
      pk[js][0] = __builtin_amdgcn_perm(__float_as_uint(e1), __float_as_uint(e0), 0x07060302);
      pk[js][1] = __builtin_amdgcn_perm(__float_as_uint(e3), __float_as_uint(e2), 0x07060302);
    }
#pragma unroll
    for (int kc = 0; kc < 2; ++kc) {
      unsigned a00 = __builtin_amdgcn_ds_bpermute(addr0, (int)pk[kc * 2][0]);
      unsigned b00 = __builtin_amdgcn_ds_bpermute(addr0, (int)pk[kc * 2 + 1][0]);
      unsigned a01 = __builtin_amdgcn_ds_bpermute(addr0, (int)pk[kc * 2][1]);
      unsigned b01 = __builtin_amdgcn_ds_bpermute(addr0, (int)pk[kc * 2 + 1][1]);
      unsigned a10 = __builtin_amdgcn_ds_bpermute(addr1, (int)pk[kc * 2][0]);
      unsigned b10 = __builtin_amdgcn_ds_bpermute(addr1, (int)pk[kc * 2 + 1][0]);
      unsigned a11 = __builtin_amdgcn_ds_bpermute(addr1, (int)pk[kc * 2][1]);
      unsigned b11 = __builtin_amdgcn_ds_bpermute(addr1, (int)pk[kc * 2 + 1][1]);
      union { unsigned u[4]; short8 s; } fa;
      fa.u[0] = bsel ? b00 : a00;
      fa.u[1] = bsel ? b01 : a01;
      fa.u[2] = bsel ? b10 : a10;
      fa.u[3] = bsel ? b11 : a11;
      Y0 = __builtin_amdgcn_mfma_f32_16x16x32_bf16(fa.s, fg[kc * 2],     Y0, 0, 0, 0);
      Y1 = __builtin_amdgcn_mfma_f32_16x16x32_bf16(fa.s, fg[kc * 2 + 1], Y1, 0, 0, 0);
    }
#pragma unroll
    for (int u = 0; u < 4; ++u) { fph[u] = nph[u]; fg[u] = ng[u]; }
  }
  float* yb = y2f + (size_t)b * 32 * N_;
#pragma unroll
  for (int reg = 0; reg < 4; ++reg) {
    atomicAdd(&yb[(size_t)n15 * N_ + iw + quad * 4 + reg], Y0[reg]);
    atomicAdd(&yb[(size_t)(16 + n15) * N_ + iw + quad * 4 + reg], Y1[reg]);
  }
}

// ---------------- final: out = (W_y(y2) + am) * x ----------------
__global__ void __launch_bounds__(256) final_k(
    const float* __restrict__ y2f, const float* __restrict__ w_w,
    const float* __restrict__ w_b, const unsigned short* __restrict__ am_cl,
    const float* __restrict__ x, float* __restrict__ out)
{
  const int n0 = (blockIdx.x * 256 + threadIdx.x) * 2;
  const int o0 = blockIdx.y * 8;
  const int b  = blockIdx.z;
  float a0[8], a1[8];
#pragma unroll
  for (int u = 0; u < 8; ++u) { a0[u] = w_b[o0 + u]; a1[u] = a0[u]; }
  for (int c = 0; c < 32; ++c) {
    float2 v = *reinterpret_cast<const float2*>(y2f + ((size_t)b * 32 + c) * N_ + n0);
#pragma unroll
    for (int u = 0; u < 8; ++u) {
      float wv = w_w[(o0 + u) * 32 + c];
      a0[u] += wv * v.x; a1[u] += wv * v.y;
    }
  }
  const short8 am0 = *reinterpret_cast<const short8*>(am_cl + ((size_t)b * N_ + n0) * 64 + o0);
  const short8 am1 = *reinterpret_cast<const short8*>(am_cl + ((size_t)b * N_ + n0 + 1) * 64 + o0);
#pragma unroll
  for (int u = 0; u < 8; ++u) {
    size_t off = ((size_t)b * 64 + o0 + u) * N_ + n0;
    float2 xv = *reinterpret_cast<const float2*>(x + off);
    float2 ov;
    ov.x = (a0[u] + bf2f((unsigned short)am0[u])) * xv.x;
    ov.y = (a1[u] + bf2f((unsigned short)am1[u])) * xv.y;
    *reinterpret_cast<float2*>(out + off) = ov;
  }
}

extern "C" void kernel_launch(void* const* d_in, const int* in_sizes, int n_in,
                              void* d_out, int out_size, void* d_ws, size_t ws_size,
                              hipStream_t stream) {
  const float* x    = (const float*)d_in[0];
  const float* d1_w = (const float*)d_in[1];
  const float* d1_b = (const float*)d_in[2];
  const float* d2_w = (const float*)d_in[3];
  const float* d2_b = (const float*)d_in[4];
  const float* d3_w = (const float*)d_in[5];
  const float* d3_b = (const float*)d_in[6];
  const float* g_w  = (const float*)d_in[7];
  const float* g_b  = (const float*)d_in[8];
  const float* th_w = (const float*)d_in[9];
  const float* th_b = (const float*)d_in[10];
  const float* ph_w = (const float*)d_in[11];
  const float* ph_b = (const float*)d_in[12];
  const float* w_w  = (const float*)d_in[13];
  const float* w_b  = (const float*)d_in[14];
  float* out = (float*)d_out;

  char* p = (char*)d_ws;
  unsigned short* am_cl = (unsigned short*)p;  p += (size_t)B_ * N_ * 64 * 2;        // 2 MB
  unsigned short* thph  = (unsigned short*)p;  p += (size_t)B_ * N_ * 64 * 2;        // 2 MB
  unsigned short* g16   = (unsigned short*)p;  p += (size_t)B_ * 32 * N_ * 2;        // 1 MB
  float* lpart          = (float*)p;           p += (size_t)8 * B_ * N_ * 4;         // 512 KB
  float* y3cl           = (float*)p;           p += (size_t)B_ * 64 * 64 * 4;        // 64 KB
  unsigned short* wpk   = (unsigned short*)p;  p += (size_t)3 * 36864 * 2;
  unsigned short* wproj = (unsigned short*)p;  p += (size_t)96 * 64 * 2;
  float* bproj          = (float*)p;           p += (size_t)96 * 4;
  // contiguous zero region: conv pads + y2f accumulator
  char* zbase = p;
  unsigned short* xclp  = (unsigned short*)p;  p += (size_t)B_ * 66 * 66 * 64 * 2;
  unsigned short* y1clp = (unsigned short*)p;  p += (size_t)B_ * 34 * 34 * 64 * 2;
  unsigned short* y2clp = (unsigned short*)p;  p += (size_t)B_ * 18 * 18 * 64 * 2;
  float* y2f            = (float*)p;           p += (size_t)B_ * 32 * N_ * 4;        // 2 MB
  const size_t zbytes = (size_t)(p - zbase);

  hipMemsetAsync(zbase, 0, zbytes, stream);
  pack_w_k<<<64, 256, 0, stream>>>(d1_w, d2_w, d3_w, th_w, ph_w, g_w,
                                   th_b, ph_b, g_b, wpk, wproj, bproj);
  pack_x_k<<<256, 256, 0, stream>>>(x, xclp);
  convmf_k<66, 32, true,  true ><<<1024, 64, 0, stream>>>(xclp,  wpk,             d1_b, y1clp, nullptr);
  convmf_k<34, 16, true,  true ><<<256,  64, 0, stream>>>(y1clp, wpk + 36864,     d2_b, y2clp, nullptr);
  convmf_k<18,  8, false, false><<<64,   64, 0, stream>>>(y2clp, wpk + 2 * 36864, d3_b, nullptr, y3cl);
  upsproj_k<<<256, 256, 0, stream>>>(y3cl, x, wproj, bproj, am_cl, thph, g16);
  attn_stats_k<<<dim3(32, 4, 8), 256, 0, stream>>>(thph, lpart);
  scale_g_k<<<dim3(16, 4), 256, 0, stream>>>(lpart, g16);
  attn_pv_k<<<dim3(64, 4, 8), 256, 0, stream>>>(thph, g16, y2f);
  final_k<<<dim3(8, 8, 4), 256, 0, stream>>>(y2f, w_w, w_b, am_cl, x, out);
}